// Round 2
// baseline (496.098 us; speedup 1.0000x reference)
//
#include <hip/hip_runtime.h>
#include <hip/hip_bf16.h>
#include <stdint.h>

// GPT self-attention, B=4 S=2048 E=2048 D=2048. FP32 in/out, bf16 MFMA internally.
// Round-6: 256^2 / BK=64 / 8-wave core restructured from 4 phases (8 barriers)
// per K-tile to 2 superphases (2 barriers): at K-tile entry the whole tile is
// LDS-resident (vmcnt(4) gate), so all s=0 fragment reads issue at once, drain
// (lgkmcnt(0)) before the single mid barrier (WAR-safe for the h0 overwrite),
// and all s=1 reads issue under the 32-MFMA s=0 cluster so their latency hides.
// Counted vmcnt(4) once per K-tile, never 0 (T4). setprio around MFMA (T5).

typedef unsigned short u16;
typedef unsigned int u32;
typedef __bf16 bf16x8 __attribute__((ext_vector_type(8)));
typedef float floatx4 __attribute__((ext_vector_type(4)));

#define DEVI __device__ __forceinline__

constexpr int Bn = 4, Sn = 2048, En = 2048, Dn = 2048;

DEVI u16 f2b(float f) {  // round-to-nearest-even f32 -> bf16
  union { float f; u32 u; } v; v.f = f;
  u32 r = v.u + 0x7FFFu + ((v.u >> 16) & 1u);
  return (u16)(r >> 16);
}

DEVI void cp16(const u16* g, u16* l) {  // async global->LDS, 16 B per lane
  __builtin_amdgcn_global_load_lds(
      (const __attribute__((address_space(1))) void*)g,
      (__attribute__((address_space(3))) void*)l, 16, 0, 0);
}

// ---- fp32 -> bf16 elementwise, n multiple of 2048; 8 elems/thread.
__global__ __launch_bounds__(256)
void cvt_kernel(const float* __restrict__ src, u16* __restrict__ dst, int n) {
  int i = (blockIdx.x * 256 + threadIdx.x) * 8;
  if (i >= n) return;
  float4 a = *(const float4*)&src[i];
  float4 b = *(const float4*)&src[i + 4];
  *(ushort4*)&dst[i]     = make_ushort4(f2b(a.x), f2b(a.y), f2b(a.z), f2b(a.w));
  *(ushort4*)&dst[i + 4] = make_ushort4(f2b(b.x), f2b(b.y), f2b(b.z), f2b(b.w));
}

// ========================= 2-superphase GEMM core ==========================
// C[m0..+256, n0..+256] += A[*,K] * Bt[*,K]^T (row-major, K contiguous), bf16,
// fp32 acc. 512 threads = 8 waves (2M x 4N); per-wave 128x64 out = acc[8][4].
// LDS (u16 elems): buf b at b*32768; A k-half s at +s*8192; B at +16384+s*8192.
// Half = 256 rows x 32 cols; 16B group g of row r stored at g ^ ((r>>1)&3)
// (pre-swizzled global source, linear DMA dest) -> conflict-free b128 reads.
// Stage order per iter m: SP0 issues (m+1,h1) A,B; SP1 issues (m+2,h0) A,B.
// vmcnt(4) at iter end leaves only the (m+2,h0) pair (4 loads) in flight =>
// kt m+1 fully landed before iter m+1 reads it.
// WAR: (m+2,h0) overwrites current-buf h0, issued only after the mid barrier,
// which every wave reaches only after lgkmcnt(0)-draining its s=0 (h0) reads.
// (m+1,h1) overwrites other-buf h1, whose readers (kt m-1 s=1) drained before
// iter m-1's final barrier. s=1 reads touch h1 only -> disjoint from (m+2,h0).
DEVI void gemmS(const u16* __restrict__ A, const u16* __restrict__ Bt,
                int lda, int ldb, int m0, int n0, int kEnd, u16* lds,
                floatx4 acc[8][4]) {
  const int tid = threadIdx.x;
  const int wave = tid >> 6, lane = tid & 63;
  const int wm = (wave >> 2) * 128, wn = (wave & 3) * 64;
  const int quad = lane >> 4, l16 = lane & 15;
  const int swe = (quad ^ ((l16 >> 1) & 3)) * 8;  // swizzled group, u16 elems
  const int nkt = kEnd >> 6;

  // staging coords: chunk c = (q*8+wave)*64 + lane, c in [0,1024); row=c>>2,
  // phys group c&3 holds logical group (c&3)^((row>>1)&3) (pre-swizzled src).
  int dstc[2];
  const u16 *Asp[2], *Bsp[2];
#pragma unroll
  for (int q = 0; q < 2; ++q) {
    int c0 = (q * 8 + wave) * 64;  // wave-uniform chunk base
    int c = c0 + lane;
    int sr = c >> 2;
    int sg = ((c & 3) ^ ((sr >> 1) & 3)) * 8;
    dstc[q] = c0 * 8;  // u16 elem offset of this issue's LDS base
    Asp[q] = A + (size_t)(m0 + sr) * lda + sg;
    Bsp[q] = Bt + (size_t)(n0 + sr) * ldb + sg;
  }
  // per-lane fragment read bases (u16 elems within a buffer)
  const int rbA = (wm + l16) * 32 + swe;
  const int rbB = 16384 + (wn + l16) * 32 + swe;

#define STAGE(ktu, isB, sh)                                                  \
  {                                                                          \
    int kc = (ktu) < nkt ? (ktu) : (nkt - 1); /* clamp src; dst keeps slot */ \
    int ks = (kc << 6) + (sh) * 32;                                          \
    int db = (((ktu) & 1) << 15) + (isB) * 16384 + (sh) * 8192;              \
    cp16(((isB) ? Bsp[0] : Asp[0]) + ks, &lds[db + dstc[0]]);                \
    cp16(((isB) ? Bsp[1] : Asp[1]) + ks, &lds[db + dstc[1]]);                \
  }

  // prologue: kt0 all 4 halves + kt1 {Ah0,Bh0}
  STAGE(0, 0, 0); STAGE(0, 1, 0); STAGE(0, 0, 1); STAGE(0, 1, 1);
  STAGE(1, 0, 0); STAGE(1, 1, 0);
  asm volatile("s_waitcnt vmcnt(4)" ::: "memory");  // kt0 landed; kt1 h0 in flight
  __builtin_amdgcn_s_barrier();

  for (int m = 0; m < nkt; ++m) {
    const int bofs = (m & 1) << 15;
    bf16x8 a0[8], b0[4], a1[8], b1[4];
    // ---- SP0: all s=0 fragment reads + next-tile h1 stage, drain, barrier.
    {
      const int ab = bofs + rbA, bb = bofs + rbB;
#pragma unroll
      for (int i = 0; i < 8; ++i) a0[i] = *(const bf16x8*)&lds[ab + i * 512];
#pragma unroll
      for (int j = 0; j < 4; ++j) b0[j] = *(const bf16x8*)&lds[bb + j * 512];
    }
    STAGE(m + 1, 0, 1); STAGE(m + 1, 1, 1);
    asm volatile("s_waitcnt lgkmcnt(0)" ::: "memory");  // own s0 reads drained
    __builtin_amdgcn_s_barrier();                       // all waves drained s0
    // ---- SP1: overwrite current h0 (now dead), issue s=1 reads (hide under
    // the s0 MFMA cluster), 32+32 MFMA, counted vmcnt, barrier.
    STAGE(m + 2, 0, 0); STAGE(m + 2, 1, 0);
    {
      const int ab = bofs + 8192 + rbA, bb = bofs + 8192 + rbB;
#pragma unroll
      for (int i = 0; i < 8; ++i) a1[i] = *(const bf16x8*)&lds[ab + i * 512];
#pragma unroll
      for (int j = 0; j < 4; ++j) b1[j] = *(const bf16x8*)&lds[bb + j * 512];
    }
    __builtin_amdgcn_sched_barrier(0);  // pin issue order: reads before MFMA-s0
    __builtin_amdgcn_s_setprio(1);
#pragma unroll
    for (int i = 0; i < 8; ++i)
#pragma unroll
      for (int j = 0; j < 4; ++j)
        acc[i][j] = __builtin_amdgcn_mfma_f32_16x16x32_bf16(a0[i], b0[j],
                                                            acc[i][j], 0, 0, 0);
    __builtin_amdgcn_sched_barrier(0);  // keep s1 cluster (and its wait) after s0
#pragma unroll
    for (int i = 0; i < 8; ++i)
#pragma unroll
      for (int j = 0; j < 4; ++j)
        acc[i][j] = __builtin_amdgcn_mfma_f32_16x16x32_bf16(a1[i], b1[j],
                                                            acc[i][j], 0, 0, 0);
    __builtin_amdgcn_s_setprio(0);
    asm volatile("s_waitcnt vmcnt(4)" ::: "memory");  // kt m+1 fully landed
    __builtin_amdgcn_s_barrier();
  }
#undef STAGE
}

// ---- QKV projection: y = x @ W^T over all tokens passed (grid.y*256 of them).
// z=0->Q, z=1->K (both [t][d]), z=2->V transposed per batch (b = t>>11).
__global__ __launch_bounds__(512, 2)
void proj_kernel(const u16* __restrict__ x, const u16* __restrict__ Wq,
                 const u16* __restrict__ Wk, const u16* __restrict__ Wv,
                 u16* __restrict__ Q, u16* __restrict__ K, u16* __restrict__ Vt) {
  __shared__ __align__(16) u16 lds[65536];
  const int z = blockIdx.z;
  const u16* W = (z == 0) ? Wq : (z == 1) ? Wk : Wv;
  const int m0 = blockIdx.y * 256, n0 = blockIdx.x * 256;
  floatx4 acc[8][4] = {};
  gemmS(x, W, En, En, m0, n0, En, lds, acc);

  const int lane = threadIdx.x & 63, wave = threadIdx.x >> 6;
  const int wm = (wave >> 2) * 128, wn = (wave & 3) * 64;
  const int quad = lane >> 4, l16 = lane & 15;

  if (z < 2) {
    u16* dst = (z == 0) ? Q : K;
#pragma unroll
    for (int mi = 0; mi < 8; ++mi) {
      int t0 = m0 + wm + mi * 16 + quad * 4;  // token index
#pragma unroll
      for (int j = 0; j < 4; ++j) {
        int gn = n0 + wn + j * 16 + l16;
#pragma unroll
        for (int r = 0; r < 4; ++r)
          dst[(size_t)(t0 + r) * Dn + gn] = f2b(acc[mi][j][r]);
      }
    }
  } else {
#pragma unroll
    for (int mi = 0; mi < 8; ++mi) {
      int t0 = m0 + wm + mi * 16 + quad * 4;
      int b = t0 >> 11, s0 = t0 & (Sn - 1);  // 256-token tiles never straddle batches
#pragma unroll
      for (int j = 0; j < 4; ++j) {
        int gn = n0 + wn + j * 16 + l16;  // d index
        *(ushort4*)&Vt[((size_t)b * Dn + gn) * Sn + s0] =
            make_ushort4(f2b(acc[mi][j][0]), f2b(acc[mi][j][1]),
                         f2b(acc[mi][j][2]), f2b(acc[mi][j][3]));
      }
    }
  }
}

// ---- scores = Q_b @ K_b^T / sqrt(D), causal; z = batch. Skipped tiles -> -1e30.
__global__ __launch_bounds__(512, 2)
void scores_kernel(const u16* __restrict__ Q, const u16* __restrict__ K,
                   float* __restrict__ Sc) {
  const int b = blockIdx.z;
  const int m0 = blockIdx.y * 256, n0 = blockIdx.x * 256;
  float* C = Sc + (size_t)b * Sn * Sn;
  if (n0 > m0 + 255) {
    const float4 f = make_float4(-1e30f, -1e30f, -1e30f, -1e30f);
    for (int idx = threadIdx.x; idx < 256 * 64; idx += 512) {
      int r = idx >> 6, c4 = (idx & 63) << 2;
      *(float4*)&C[(size_t)(m0 + r) * Sn + n0 + c4] = f;
    }
    return;
  }
  __shared__ __align__(16) u16 lds[65536];
  floatx4 acc[8][4] = {};
  gemmS(Q + (size_t)b * Sn * Dn, K + (size_t)b * Sn * Dn, Dn, Dn, m0, n0, Dn,
        lds, acc);

  const float inv_scale = 0.022097086912079608f;  // 1/sqrt(2048)
  const int lane = threadIdx.x & 63, wave = threadIdx.x >> 6;
  const int wm = (wave >> 2) * 128, wn = (wave & 3) * 64;
  const int quad = lane >> 4, l16 = lane & 15;
#pragma unroll
  for (int mi = 0; mi < 8; ++mi) {
    int gm0 = m0 + wm + mi * 16 + quad * 4;
#pragma unroll
    for (int j = 0; j < 4; ++j) {
      int gn = n0 + wn + j * 16 + l16;
#pragma unroll
      for (int r = 0; r < 4; ++r) {
        float v = acc[mi][j][r] * inv_scale;
        if (gn > gm0 + r) v = -1e30f;
        C[(size_t)(gm0 + r) * Sn + gn] = v;
      }
    }
  }
}

// ---- row softmax over 2048 fp32; write attn bf16 in-place (u16 pitch 2*Sn).
__global__ __launch_bounds__(256)
void softmax_kernel(float* __restrict__ Sc) {
  float* sr = Sc + (size_t)blockIdx.x * Sn;
  const int t = threadIdx.x;
  float4 v0 = ((const float4*)sr)[t];
  float4 v1 = ((const float4*)sr)[t + 256];
  float m = fmaxf(fmaxf(fmaxf(v0.x, v0.y), fmaxf(v0.z, v0.w)),
                  fmaxf(fmaxf(v1.x, v1.y), fmaxf(v1.z, v1.w)));
#pragma unroll
  for (int off = 32; off; off >>= 1) m = fmaxf(m, __shfl_xor(m, off));
  __shared__ float redm[4], reds[4];
  if ((t & 63) == 0) redm[t >> 6] = m;
  __syncthreads();
  m = fmaxf(fmaxf(redm[0], redm[1]), fmaxf(redm[2], redm[3]));

  float e[8];
  e[0] = __expf(v0.x - m); e[1] = __expf(v0.y - m);
  e[2] = __expf(v0.z - m); e[3] = __expf(v0.w - m);
  e[4] = __expf(v1.x - m); e[5] = __expf(v1.y - m);
  e[6] = __expf(v1.z - m); e[7] = __expf(v1.w - m);
  float s = ((e[0] + e[1]) + (e[2] + e[3])) + ((e[4] + e[5]) + (e[6] + e[7]));
#pragma unroll
  for (int off = 32; off; off >>= 1) s += __shfl_xor(s, off);
  if ((t & 63) == 0) reds[t >> 6] = s;
  __syncthreads();
  s = (reds[0] + reds[1]) + (reds[2] + reds[3]);
  float inv = 1.0f / s;

  u16* ar = (u16*)sr;  // all global reads above; in-place bf16 write is safe
  *(ushort4*)&ar[t * 4] =
      make_ushort4(f2b(e[0] * inv), f2b(e[1] * inv), f2b(e[2] * inv), f2b(e[3] * inv));
  *(ushort4*)&ar[(t + 256) * 4] =
      make_ushort4(f2b(e[4] * inv), f2b(e[5] * inv), f2b(e[6] * inv), f2b(e[7] * inv));
}

// ---- out_b = attn @ V via Vt; z = batch; K-loop truncated at diagonal. FP32 out.
__global__ __launch_bounds__(512, 2)
void pv_kernel(const float* __restrict__ Sc, const u16* __restrict__ Vt,
               float* __restrict__ out) {
  const int b = blockIdx.z;
  const int m0 = blockIdx.y * 256, n0 = blockIdx.x * 256;
  __shared__ __align__(16) u16 lds[65536];
  floatx4 acc[8][4] = {};
  const u16* P = (const u16*)(Sc + (size_t)b * Sn * Sn);  // bf16 attn, pitch 2*Sn
  gemmS(P, Vt + (size_t)b * Dn * Sn, 2 * Sn, Sn, m0, n0, m0 + 256, lds, acc);

  const int lane = threadIdx.x & 63, wave = threadIdx.x >> 6;
  const int wm = (wave >> 2) * 128, wn = (wave & 3) * 64;
  const int quad = lane >> 4, l16 = lane & 15;
  float* ob = out + (size_t)b * Sn * Dn;
#pragma unroll
  for (int mi = 0; mi < 8; ++mi) {
    int gm0 = m0 + wm + mi * 16 + quad * 4;
#pragma unroll
    for (int j = 0; j < 4; ++j) {
      int gn = n0 + wn + j * 16 + l16;
#pragma unroll
      for (int r = 0; r < 4; ++r)
        ob[(size_t)(gm0 + r) * Dn + gn] = acc[mi][j][r];
    }
  }
}

extern "C" void kernel_launch(void* const* d_in, const int* in_sizes, int n_in,
                              void* d_out, int out_size, void* d_ws, size_t ws_size,
                              hipStream_t stream) {
  const float* x  = (const float*)d_in[0];   // setup_inputs order: x, Wk, Wq, Wv (fp32)
  const float* Wk = (const float*)d_in[1];
  const float* Wq = (const float*)d_in[2];
  const float* Wv = (const float*)d_in[3];
  float* out = (float*)d_out;

  dim3 blk(256), blk5(512);
  const int nW = Dn * En;                    // 4M elems per weight
  const size_t MiB = 1ull << 20;

  if (ws_size >= 184 * MiB) {
    // ---- fused path: Wqb|Wkb|Wvb | xb(all) | K(all) | Vt(all) | Sc(all fp32)
    u16* Wqb = (u16*)d_ws;
    u16* Wkb = Wqb + (size_t)nW;
    u16* Wvb = Wkb + (size_t)nW;
    u16* xb  = Wvb + (size_t)nW;             // [8192][2048]
    u16* Kall = xb + (size_t)Bn * Sn * En;   // [8192][2048]
    u16* Vtall = Kall + (size_t)Bn * Sn * Dn;  // [b][d][s]
    float* Sc = (float*)(Vtall + (size_t)Bn * Dn * Sn);  // [b][s][s]
    u16* Qall = (u16*)out;                   // 32 MiB of the 64 MiB out; pv overwrites

    cvt_kernel<<<nW / 2048, blk, 0, stream>>>(Wq, Wqb, nW);
    cvt_kernel<<<nW / 2048, blk, 0, stream>>>(Wk, Wkb, nW);
    cvt_kernel<<<nW / 2048, blk, 0, stream>>>(Wv, Wvb, nW);
    cvt_kernel<<<(Bn * Sn * En) / 2048, blk, 0, stream>>>(x, xb, Bn * Sn * En);
    proj_kernel<<<dim3(Dn / 256, (Bn * Sn) / 256, 3), blk5, 0, stream>>>(
        xb, Wqb, Wkb, Wvb, Qall, Kall, Vtall);
    scores_kernel<<<dim3(Sn / 256, Sn / 256, Bn), blk5, 0, stream>>>(Qall, Kall, Sc);
    softmax_kernel<<<dim3(Bn * Sn), blk, 0, stream>>>(Sc);
    pv_kernel<<<dim3(Dn / 256, Sn / 256, Bn), blk5, 0, stream>>>(Sc, Vtall, out);
  } else {
    // ---- sequential fallback (56 MiB): Wqb|Wkb|Wvb | Sc (xb aliased) | Kb | Vtb
    u16* Wqb = (u16*)d_ws;
    u16* Wkb = Wqb + (size_t)nW;
    u16* Wvb = Wkb + (size_t)nW;
    float* Sc = (float*)(Wvb + (size_t)nW);
    u16* xb  = (u16*)Sc;                     // dead once scores_kernel runs
    u16* Kb  = (u16*)(Sc + (size_t)Sn * Sn);
    u16* Vtb = Kb + (size_t)Sn * Dn;

    cvt_kernel<<<nW / 2048, blk, 0, stream>>>(Wq, Wqb, nW);
    cvt_kernel<<<nW / 2048, blk, 0, stream>>>(Wk, Wkb, nW);
    cvt_kernel<<<nW / 2048, blk, 0, stream>>>(Wv, Wvb, nW);
    for (int b = 0; b < Bn; ++b) {
      const float* xf = x + (size_t)b * Sn * En;
      float* outb = out + (size_t)b * Sn * Dn;
      u16* Qb = (u16*)outb;                  // bf16 Q in out_b's region; pv overwrites
      cvt_kernel<<<(Sn * En) / 2048, blk, 0, stream>>>(xf, xb, Sn * En);
      proj_kernel<<<dim3(Dn / 256, Sn / 256, 3), blk5, 0, stream>>>(xb, Wqb, Wkb, Wvb,
                                                                    Qb, Kb, Vtb);
      scores_kernel<<<dim3(Sn / 256, Sn / 256, 1), blk5, 0, stream>>>(Qb, Kb, Sc);
      softmax_kernel<<<dim3(Sn), blk, 0, stream>>>(Sc);
      pv_kernel<<<dim3(Dn / 256, Sn / 256, 1), blk5, 0, stream>>>(Sc, Vtb, outb);
    }
  }
}

// Round 4
// 494.459 us; speedup vs baseline: 1.0033x; 1.0033x over previous
//
#include <hip/hip_runtime.h>
#include <hip/hip_bf16.h>
#include <stdint.h>

// GPT self-attention, B=4 S=2048 E=2048 D=2048. FP32 in/out, bf16 MFMA internally.
// Round-8: race-fixed rotated pipeline. Round-7's NaN: next-tile s0 fragment
// reads were issued after a per-wave vmcnt(4) but BEFORE a barrier -> read LDS
// that OTHER waves' global_load_lds hadn't written (vmcnt is per-wave only).
// Fix: mid-iter gate "vmcnt(4); s_barrier; sched_barrier(0)" (B2), next-s0
// reads after B2 under the tail 16-MFMA cluster. 2 barriers/iter total (end
// barrier dropped; its WAR role is covered by next iter's lgkmcnt(0)+B1).
// Prologue preload moved after the prologue barrier.

typedef unsigned short u16;
typedef unsigned int u32;
typedef __bf16 bf16x8 __attribute__((ext_vector_type(8)));
typedef float floatx4 __attribute__((ext_vector_type(4)));

#define DEVI __device__ __forceinline__

constexpr int Bn = 4, Sn = 2048, En = 2048, Dn = 2048;

DEVI u16 f2b(float f) {  // round-to-nearest-even f32 -> bf16
  union { float f; u32 u; } v; v.f = f;
  u32 r = v.u + 0x7FFFu + ((v.u >> 16) & 1u);
  return (u16)(r >> 16);
}

DEVI void cp16(const u16* g, u16* l) {  // async global->LDS, 16 B per lane
  __builtin_amdgcn_global_load_lds(
      (const __attribute__((address_space(1))) void*)g,
      (__attribute__((address_space(3))) void*)l, 16, 0, 0);
}

// ---- fp32 -> bf16 elementwise, n multiple of 2048; 8 elems/thread.
__global__ __launch_bounds__(256)
void cvt_kernel(const float* __restrict__ src, u16* __restrict__ dst, int n) {
  int i = (blockIdx.x * 256 + threadIdx.x) * 8;
  if (i >= n) return;
  float4 a = *(const float4*)&src[i];
  float4 b = *(const float4*)&src[i + 4];
  *(ushort4*)&dst[i]     = make_ushort4(f2b(a.x), f2b(a.y), f2b(a.z), f2b(a.w));
  *(ushort4*)&dst[i + 4] = make_ushort4(f2b(b.x), f2b(b.y), f2b(b.z), f2b(b.w));
}

// ===================== rotated-pipeline GEMM core ==========================
// C[m0..+256, n0..+256] += A[*,K] * Bt[*,K]^T (row-major, K contiguous), bf16,
// fp32 acc. 512 threads = 8 waves (2M x 4N); per-wave 128x64 out = acc[8][4].
// LDS (u16 elems): buf b at b*32768; A k-half s at +s*8192; B at +16384+s*8192.
// Half = 256 rows x 32 cols; 16B group g of row r stored at g ^ ((r>>1)&3)
// (pre-swizzled global source, linear DMA dest) -> conflict-free b128 reads.
//
// Iter m (cur buf = m&1):
//  1. STAGE(m+1,h1)[other-buf h1; its old readers drained before iter m-1's B2
//     (compiler lgkm wait before first s1 MFMA) -> safe];
//     lgkmcnt(0) [drains this wave's kt-m s0 reads from iter m-1 tail];
//     B1 + sched_barrier  [all waves drained -> cur h0 overwritable].
//  2. STAGE(m+2,h0) into cur h0; read a1/b1 (cur h1, landed via prev B2).
//  3. 32 MFMA s0 (covers a1/b1 drain)  [setprio 1]
//  4. 16 MFMA s1 (first half; compiler emits counted lgkm wait before it).
//  5. vmcnt(4); B2 + sched_barrier.  Ledger: outstanding = kt(m+1)h0[4 from
//     iter m-1 step 2] + kt(m+1)h1[4, step 1] + kt(m+2)h0[4, step 2] = 12;
//     wait <=4 drains the 8 oldest = kt m+1 complete, per wave; B2 makes it
//     all-waves. Leaves kt(m+2)h0 in flight (never 0 -> T4).
//  6. read next a0/b0 (other buf h0 = kt m+1 s0, now landed all-waves).
//  7. 16 MFMA s1 (second half; covers next-s0 drain)  [setprio 0]
//  No end barrier: next iter's lgkm(0)+B1 is the WAR gate for both cur-h0 and
//  the just-issued a0/b0 reads' slot.
DEVI void gemmS(const u16* __restrict__ A, const u16* __restrict__ Bt,
                int lda, int ldb, int m0, int n0, int kEnd, u16* lds,
                floatx4 acc[8][4]) {
  const int tid = threadIdx.x;
  const int wave = tid >> 6, lane = tid & 63;
  const int wm = (wave >> 2) * 128, wn = (wave & 3) * 64;
  const int quad = lane >> 4, l16 = lane & 15;
  const int swe = (quad ^ ((l16 >> 1) & 3)) * 8;  // swizzled group, u16 elems
  const int nkt = kEnd >> 6;

  // staging coords: chunk c = (q*8+wave)*64 + lane, c in [0,1024); row=c>>2,
  // phys group c&3 holds logical group (c&3)^((row>>1)&3) (pre-swizzled src).
  int dstc[2];
  const u16 *Asp[2], *Bsp[2];
#pragma unroll
  for (int q = 0; q < 2; ++q) {
    int c0 = (q * 8 + wave) * 64;  // wave-uniform chunk base
    int c = c0 + lane;
    int sr = c >> 2;
    int sg = ((c & 3) ^ ((sr >> 1) & 3)) * 8;
    dstc[q] = c0 * 8;  // u16 elem offset of this issue's LDS base
    Asp[q] = A + (size_t)(m0 + sr) * lda + sg;
    Bsp[q] = Bt + (size_t)(n0 + sr) * ldb + sg;
  }
  // per-lane fragment read bases (u16 elems within a buffer)
  const int rbA = (wm + l16) * 32 + swe;
  const int rbB = 16384 + (wn + l16) * 32 + swe;

#define STAGE(ktu, isB, sh)                                                  \
  {                                                                          \
    int kc = (ktu) < nkt ? (ktu) : (nkt - 1); /* clamp src; dst keeps slot */ \
    int ks = (kc << 6) + (sh) * 32;                                          \
    int db = (((ktu) & 1) << 15) + (isB) * 16384 + (sh) * 8192;              \
    cp16(((isB) ? Bsp[0] : Asp[0]) + ks, &lds[db + dstc[0]]);                \
    cp16(((isB) ? Bsp[1] : Asp[1]) + ks, &lds[db + dstc[1]]);                \
  }

  bf16x8 a0[8], b0[4];
  // prologue: kt0 all 4 halves + kt1 {Ah0,Bh0}; gate kt0 (vmcnt+barrier =
  // all-waves landed); THEN preload kt0 s0 frags (post-barrier -> race-free).
  STAGE(0, 0, 0); STAGE(0, 1, 0); STAGE(0, 0, 1); STAGE(0, 1, 1);
  STAGE(1, 0, 0); STAGE(1, 1, 0);
  asm volatile("s_waitcnt vmcnt(4)" ::: "memory");  // kt0 landed; (1,h0) in flight
  __builtin_amdgcn_s_barrier();
  __builtin_amdgcn_sched_barrier(0);
#pragma unroll
  for (int i = 0; i < 8; ++i) a0[i] = *(const bf16x8*)&lds[rbA + i * 512];
#pragma unroll
  for (int j = 0; j < 4; ++j) b0[j] = *(const bf16x8*)&lds[rbB + j * 512];

  for (int m = 0; m < nkt; ++m) {
    const int bofs = (m & 1) << 15;
    const int nofs = bofs ^ 32768;
    bf16x8 a1[8], b1[4];
    // -- step 1: other-buf h1 stage; drain own s0 reads; B1 (h0 WAR gate)
    STAGE(m + 1, 0, 1); STAGE(m + 1, 1, 1);
    asm volatile("s_waitcnt lgkmcnt(0)" ::: "memory");
    __builtin_amdgcn_s_barrier();
    __builtin_amdgcn_sched_barrier(0);
    // -- step 2: overwrite cur h0; issue s1 fragment reads
    STAGE(m + 2, 0, 0); STAGE(m + 2, 1, 0);
    {
      const int ab = bofs + 8192 + rbA, bb = bofs + 8192 + rbB;
#pragma unroll
      for (int i = 0; i < 8; ++i) a1[i] = *(const bf16x8*)&lds[ab + i * 512];
#pragma unroll
      for (int j = 0; j < 4; ++j) b1[j] = *(const bf16x8*)&lds[bb + j * 512];
    }
    __builtin_amdgcn_sched_barrier(0);  // pin: s1 reads issued before MFMA-s0
    __builtin_amdgcn_s_setprio(1);
    // -- step 3: 32 MFMA s0 (covers a1/b1 drain)
#pragma unroll
    for (int i = 0; i < 8; ++i)
#pragma unroll
      for (int j = 0; j < 4; ++j)
        acc[i][j] = __builtin_amdgcn_mfma_f32_16x16x32_bf16(a0[i], b0[j],
                                                            acc[i][j], 0, 0, 0);
    __builtin_amdgcn_sched_barrier(0);
    // -- step 4: 16 MFMA s1 first half (compiler lgkm wait lands here)
#pragma unroll
    for (int i = 0; i < 4; ++i)
#pragma unroll
      for (int j = 0; j < 4; ++j)
        acc[i][j] = __builtin_amdgcn_mfma_f32_16x16x32_bf16(a1[i], b1[j],
                                                            acc[i][j], 0, 0, 0);
    __builtin_amdgcn_sched_barrier(0);
    // -- step 5: B2 — all-waves DMA-visibility gate for kt m+1
    asm volatile("s_waitcnt vmcnt(4)" ::: "memory");
    __builtin_amdgcn_s_barrier();
    __builtin_amdgcn_sched_barrier(0);
    // -- step 6: next K-tile s0 fragments (safe post-B2)
    {
      const int ab = nofs + rbA, bb = nofs + rbB;
#pragma unroll
      for (int i = 0; i < 8; ++i) a0[i] = *(const bf16x8*)&lds[ab + i * 512];
#pragma unroll
      for (int j = 0; j < 4; ++j) b0[j] = *(const bf16x8*)&lds[bb + j * 512];
    }
    __builtin_amdgcn_sched_barrier(0);
    // -- step 7: 16 MFMA s1 second half (covers next-s0 drain)
#pragma unroll
    for (int i = 4; i < 8; ++i)
#pragma unroll
      for (int j = 0; j < 4; ++j)
        acc[i][j] = __builtin_amdgcn_mfma_f32_16x16x32_bf16(a1[i], b1[j],
                                                            acc[i][j], 0, 0, 0);
    __builtin_amdgcn_s_setprio(0);
  }
#undef STAGE
}

// ---- QKV projection: y = x @ W^T over all tokens passed (grid.y*256 of them).
// z=0->Q, z=1->K (both [t][d]), z=2->V transposed per batch (b = t>>11).
__global__ __launch_bounds__(512, 2)
void proj_kernel(const u16* __restrict__ x, const u16* __restrict__ Wq,
                 const u16* __restrict__ Wk, const u16* __restrict__ Wv,
                 u16* __restrict__ Q, u16* __restrict__ K, u16* __restrict__ Vt) {
  __shared__ __align__(16) u16 lds[65536];
  const int z = blockIdx.z;
  const u16* W = (z == 0) ? Wq : (z == 1) ? Wk : Wv;
  const int m0 = blockIdx.y * 256, n0 = blockIdx.x * 256;
  floatx4 acc[8][4] = {};
  gemmS(x, W, En, En, m0, n0, En, lds, acc);

  const int lane = threadIdx.x & 63, wave = threadIdx.x >> 6;
  const int wm = (wave >> 2) * 128, wn = (wave & 3) * 64;
  const int quad = lane >> 4, l16 = lane & 15;

  if (z < 2) {
    u16* dst = (z == 0) ? Q : K;
#pragma unroll
    for (int mi = 0; mi < 8; ++mi) {
      int t0 = m0 + wm + mi * 16 + quad * 4;  // token index
#pragma unroll
      for (int j = 0; j < 4; ++j) {
        int gn = n0 + wn + j * 16 + l16;
#pragma unroll
        for (int r = 0; r < 4; ++r)
          dst[(size_t)(t0 + r) * Dn + gn] = f2b(acc[mi][j][r]);
      }
    }
  } else {
#pragma unroll
    for (int mi = 0; mi < 8; ++mi) {
      int t0 = m0 + wm + mi * 16 + quad * 4;
      int b = t0 >> 11, s0 = t0 & (Sn - 1);  // 256-token tiles never straddle batches
#pragma unroll
      for (int j = 0; j < 4; ++j) {
        int gn = n0 + wn + j * 16 + l16;  // d index
        *(ushort4*)&Vt[((size_t)b * Dn + gn) * Sn + s0] =
            make_ushort4(f2b(acc[mi][j][0]), f2b(acc[mi][j][1]),
                         f2b(acc[mi][j][2]), f2b(acc[mi][j][3]));
      }
    }
  }
}

// ---- scores = Q_b @ K_b^T / sqrt(D), causal; z = batch. Skipped tiles -> -1e30.
__global__ __launch_bounds__(512, 2)
void scores_kernel(const u16* __restrict__ Q, const u16* __restrict__ K,
                   float* __restrict__ Sc) {
  const int b = blockIdx.z;
  const int m0 = blockIdx.y * 256, n0 = blockIdx.x * 256;
  float* C = Sc + (size_t)b * Sn * Sn;
  if (n0 > m0 + 255) {
    const float4 f = make_float4(-1e30f, -1e30f, -1e30f, -1e30f);
    for (int idx = threadIdx.x; idx < 256 * 64; idx += 512) {
      int r = idx >> 6, c4 = (idx & 63) << 2;
      *(float4*)&C[(size_t)(m0 + r) * Sn + n0 + c4] = f;
    }
    return;
  }
  __shared__ __align__(16) u16 lds[65536];
  floatx4 acc[8][4] = {};
  gemmS(Q + (size_t)b * Sn * Dn, K + (size_t)b * Sn * Dn, Dn, Dn, m0, n0, Dn,
        lds, acc);

  const float inv_scale = 0.022097086912079608f;  // 1/sqrt(2048)
  const int lane = threadIdx.x & 63, wave = threadIdx.x >> 6;
  const int wm = (wave >> 2) * 128, wn = (wave & 3) * 64;
  const int quad = lane >> 4, l16 = lane & 15;
#pragma unroll
  for (int mi = 0; mi < 8; ++mi) {
    int gm0 = m0 + wm + mi * 16 + quad * 4;
#pragma unroll
    for (int j = 0; j < 4; ++j) {
      int gn = n0 + wn + j * 16 + l16;
#pragma unroll
      for (int r = 0; r < 4; ++r) {
        float v = acc[mi][j][r] * inv_scale;
        if (gn > gm0 + r) v = -1e30f;
        C[(size_t)(gm0 + r) * Sn + gn] = v;
      }
    }
  }
}

// ---- row softmax over 2048 fp32; write attn bf16 in-place (u16 pitch 2*Sn).
__global__ __launch_bounds__(256)
void softmax_kernel(float* __restrict__ Sc) {
  float* sr = Sc + (size_t)blockIdx.x * Sn;
  const int t = threadIdx.x;
  float4 v0 = ((const float4*)sr)[t];
  float4 v1 = ((const float4*)sr)[t + 256];
  float m = fmaxf(fmaxf(fmaxf(v0.x, v0.y), fmaxf(v0.z, v0.w)),
                  fmaxf(fmaxf(v1.x, v1.y), fmaxf(v1.z, v1.w)));
#pragma unroll
  for (int off = 32; off; off >>= 1) m = fmaxf(m, __shfl_xor(m, off));
  __shared__ float redm[4], reds[4];
  if ((t & 63) == 0) redm[t >> 6] = m;
  __syncthreads();
  m = fmaxf(fmaxf(redm[0], redm[1]), fmaxf(redm[2], redm[3]));

  float e[8];
  e[0] = __expf(v0.x - m); e[1] = __expf(v0.y - m);
  e[2] = __expf(v0.z - m); e[3] = __expf(v0.w - m);
  e[4] = __expf(v1.x - m); e[5] = __expf(v1.y - m);
  e[6] = __expf(v1.z - m); e[7] = __expf(v1.w - m);
  float s = ((e[0] + e[1]) + (e[2] + e[3])) + ((e[4] + e[5]) + (e[6] + e[7]));
#pragma unroll
  for (int off = 32; off; off >>= 1) s += __shfl_xor(s, off);
  if ((t & 63) == 0) reds[t >> 6] = s;
  __syncthreads();
  s = (reds[0] + reds[1]) + (reds[2] + reds[3]);
  float inv = 1.0f / s;

  u16* ar = (u16*)sr;  // all global reads above; in-place bf16 write is safe
  *(ushort4*)&ar[t * 4] =
      make_ushort4(f2b(e[0] * inv), f2b(e[1] * inv), f2b(e[2] * inv), f2b(e[3] * inv));
  *(ushort4*)&ar[(t + 256) * 4] =
      make_ushort4(f2b(e[4] * inv), f2b(e[5] * inv), f2b(e[6] * inv), f2b(e[7] * inv));
}

// ---- out_b = attn @ V via Vt; z = batch; K-loop truncated at diagonal. FP32 out.
__global__ __launch_bounds__(512, 2)
void pv_kernel(const float* __restrict__ Sc, const u16* __restrict__ Vt,
               float* __restrict__ out) {
  const int b = blockIdx.z;
  const int m0 = blockIdx.y * 256, n0 = blockIdx.x * 256;
  __shared__ __align__(16) u16 lds[65536];
  floatx4 acc[8][4] = {};
  const u16* P = (const u16*)(Sc + (size_t)b * Sn * Sn);  // bf16 attn, pitch 2*Sn
  gemmS(P, Vt + (size_t)b * Dn * Sn, 2 * Sn, Sn, m0, n0, m0 + 256, lds, acc);

  const int lane = threadIdx.x & 63, wave = threadIdx.x >> 6;
  const int wm = (wave >> 2) * 128, wn = (wave & 3) * 64;
  const int quad = lane >> 4, l16 = lane & 15;
  float* ob = out + (size_t)b * Sn * Dn;
#pragma unroll
  for (int mi = 0; mi < 8; ++mi) {
    int gm0 = m0 + wm + mi * 16 + quad * 4;
#pragma unroll
    for (int j = 0; j < 4; ++j) {
      int gn = n0 + wn + j * 16 + l16;
#pragma unroll
      for (int r = 0; r < 4; ++r)
        ob[(size_t)(gm0 + r) * Dn + gn] = acc[mi][j][r];
    }
  }
}

extern "C" void kernel_launch(void* const* d_in, const int* in_sizes, int n_in,
                              void* d_out, int out_size, void* d_ws, size_t ws_size,
                              hipStream_t stream) {
  const float* x  = (const float*)d_in[0];   // setup_inputs order: x, Wk, Wq, Wv (fp32)
  const float* Wk = (const float*)d_in[1];
  const float* Wq = (const float*)d_in[2];
  const float* Wv = (const float*)d_in[3];
  float* out = (float*)d_out;

  dim3 blk(256), blk5(512);
  const int nW = Dn * En;                    // 4M elems per weight
  const size_t MiB = 1ull << 20;

  if (ws_size >= 184 * MiB) {
    // ---- fused path: Wqb|Wkb|Wvb | xb(all) | K(all) | Vt(all) | Sc(all fp32)
    u16* Wqb = (u16*)d_ws;
    u16* Wkb = Wqb + (size_t)nW;
    u16* Wvb = Wkb + (size_t)nW;
    u16* xb  = Wvb + (size_t)nW;             // [8192][2048]
    u16* Kall = xb + (size_t)Bn * Sn * En;   // [8192][2048]
    u16* Vtall = Kall + (size_t)Bn * Sn * Dn;  // [b][d][s]
    float* Sc = (float*)(Vtall + (size_t)Bn * Dn * Sn);  // [b][s][s]
    u16* Qall = (u16*)out;                   // 32 MiB of the 64 MiB out; pv overwrites

    cvt_kernel<<<nW / 2048, blk, 0, stream>>>(Wq, Wqb, nW);
    cvt_kernel<<<nW / 2048, blk, 0, stream>>>(Wk, Wkb, nW);
    cvt_kernel<<<nW / 2048, blk, 0, stream>>>(Wv, Wvb, nW);
    cvt_kernel<<<(Bn * Sn * En) / 2048, blk, 0, stream>>>(x, xb, Bn * Sn * En);
    proj_kernel<<<dim3(Dn / 256, (Bn * Sn) / 256, 3), blk5, 0, stream>>>(
        xb, Wqb, Wkb, Wvb, Qall, Kall, Vtall);
    scores_kernel<<<dim3(Sn / 256, Sn / 256, Bn), blk5, 0, stream>>>(Qall, Kall, Sc);
    softmax_kernel<<<dim3(Bn * Sn), blk, 0, stream>>>(Sc);
    pv_kernel<<<dim3(Dn / 256, Sn / 256, Bn), blk5, 0, stream>>>(Sc, Vtall, out);
  } else {
    // ---- sequential fallback (56 MiB): Wqb|Wkb|Wvb | Sc (xb aliased) | Kb | Vtb
    u16* Wqb = (u16*)d_ws;
    u16* Wkb = Wqb + (size_t)nW;
    u16* Wvb = Wkb + (size_t)nW;
    float* Sc = (float*)(Wvb + (size_t)nW);
    u16* xb  = (u16*)Sc;                     // dead once scores_kernel runs
    u16* Kb  = (u16*)(Sc + (size_t)Sn * Sn);
    u16* Vtb = Kb + (size_t)Sn * Dn;

    cvt_kernel<<<nW / 2048, blk, 0, stream>>>(Wq, Wqb, nW);
    cvt_kernel<<<nW / 2048, blk, 0, stream>>>(Wk, Wkb, nW);
    cvt_kernel<<<nW / 2048, blk, 0, stream>>>(Wv, Wvb, nW);
    for (int b = 0; b < Bn; ++b) {
      const float* xf = x + (size_t)b * Sn * En;
      float* outb = out + (size_t)b * Sn * Dn;
      u16* Qb = (u16*)outb;                  // bf16 Q in out_b's region; pv overwrites
      cvt_kernel<<<(Sn * En) / 2048, blk, 0, stream>>>(xf, xb, Sn * En);
      proj_kernel<<<dim3(Dn / 256, Sn / 256, 3), blk5, 0, stream>>>(xb, Wqb, Wkb, Wvb,
                                                                    Qb, Kb, Vtb);
      scores_kernel<<<dim3(Sn / 256, Sn / 256, 1), blk5, 0, stream>>>(Qb, Kb, Sc);
      softmax_kernel<<<dim3(Sn), blk, 0, stream>>>(Sc);
      pv_kernel<<<dim3(Dn / 256, Sn / 256, 1), blk5, 0, stream>>>(Sc, Vtb, outb);
    }
  }
}

// Round 6
// 489.792 us; speedup vs baseline: 1.0129x; 1.0095x over previous
//
#include <hip/hip_runtime.h>
#include <hip/hip_bf16.h>
#include <stdint.h>

// GPT self-attention, B=4 S=2048 E=2048 D=2048. FP32 in/out, bf16 MFMA internally.
// Round-10: identical resubmit of round-9 hybrid (round-9 bench was an infra
// failure: container died twice; no result). Rationale unchanged:
// proj (768 blocks > 256 CUs) -> 128^2 core (round-0, proven 190us, 52% util,
// 3 blocks/CU). scores (144 GEMM blocks) + pv (256 blocks) fit one grid-wave
// -> 1 block/CU free -> 256^2 rotated-pipeline core (round-4, proven correct,
// ~17us faster for these two stages per round-5 decomposition).

typedef unsigned short u16;
typedef unsigned int u32;
typedef __bf16 bf16x8 __attribute__((ext_vector_type(8)));
typedef float floatx4 __attribute__((ext_vector_type(4)));

#define DEVI __device__ __forceinline__

constexpr int Bn = 4, Sn = 2048, En = 2048, Dn = 2048;

DEVI u16 f2b(float f) {  // round-to-nearest-even f32 -> bf16
  union { float f; u32 u; } v; v.f = f;
  u32 r = v.u + 0x7FFFu + ((v.u >> 16) & 1u);
  return (u16)(r >> 16);
}

DEVI void cp16(const u16* g, u16* l) {  // async global->LDS, 16 B per lane
  __builtin_amdgcn_global_load_lds(
      (const __attribute__((address_space(1))) void*)g,
      (__attribute__((address_space(3))) void*)l, 16, 0, 0);
}

// ---- fp32 -> bf16 elementwise, n multiple of 2048; 8 elems/thread.
__global__ __launch_bounds__(256)
void cvt_kernel(const float* __restrict__ src, u16* __restrict__ dst, int n) {
  int i = (blockIdx.x * 256 + threadIdx.x) * 8;
  if (i >= n) return;
  float4 a = *(const float4*)&src[i];
  float4 b = *(const float4*)&src[i + 4];
  *(ushort4*)&dst[i]     = make_ushort4(f2b(a.x), f2b(a.y), f2b(a.z), f2b(a.w));
  *(ushort4*)&dst[i + 4] = make_ushort4(f2b(b.x), f2b(b.y), f2b(b.z), f2b(b.w));
}

// ======================= 128^2 core (proj) =================================
// C[m0..+128, n0..+128] += A[*,K] * Bt[*,K]^T (row-major, K contiguous), bf16,
// fp32 acc. 256 threads = 4 waves (2x2), per-wave 64x64 out = acc[4][4].
// LDS tiles 128x64 unpadded (LP=64), 8-elem group g of row r stored at g^(r&7)
// via pre-swizzled global source (linear DMA dest). 32 KiB LDS, VGPR 60 ->
// 3 blocks/CU co-resident: inter-block overlap covers staging stalls (52% util).
DEVI void gemm_core(const u16* __restrict__ A, const u16* __restrict__ Bt,
                    int lda, int ldb, int m0, int n0, int kEnd,
                    u16* As, u16* Bs, floatx4 acc[4][4]) {
  const int tid = threadIdx.x;
  const int lane = tid & 63;
  const int wave = tid >> 6;
  const int wm = (wave >> 1) * 64;
  const int wn = (wave & 1) * 64;
  const int quad = lane >> 4;
  const int l16 = lane & 15;
  const int sw = l16 & 7;  // r&7 for fragment rows (wm,wn,i*16 are multiples of 8)

  // per-lane staging coords, constant across k-iters
  int srow[4], sgl[4], sdst[4];
#pragma unroll
  for (int u = 0; u < 4; ++u) {
    int c0 = wave * 256 + u * 64;       // wave-uniform chunk base
    int c = c0 + lane;                  // this lane's 16B chunk
    srow[u] = c >> 3;
    sgl[u] = (c & 7) ^ (srow[u] & 7);   // logical column-group under swizzle
    sdst[u] = c0 * 8;                   // LDS elem offset (wave-uniform)
  }

  for (int k0 = 0; k0 < kEnd; k0 += 64) {
#pragma unroll
    for (int u = 0; u < 4; ++u) {
      cp16(&A[(size_t)(m0 + srow[u]) * lda + k0 + sgl[u] * 8], &As[sdst[u]]);
      cp16(&Bt[(size_t)(n0 + srow[u]) * ldb + k0 + sgl[u] * 8], &Bs[sdst[u]]);
    }
    __syncthreads();  // drains vmcnt -> DMA complete
#pragma unroll
    for (int s = 0; s < 2; ++s) {
      const int gcol = ((s * 4 + quad) ^ sw) * 8;  // swizzled group offset (elems)
      bf16x8 af[4], bfr[4];
#pragma unroll
      for (int i = 0; i < 4; ++i)
        af[i] = *(const bf16x8*)&As[(wm + i * 16 + l16) * 64 + gcol];
#pragma unroll
      for (int j = 0; j < 4; ++j)
        bfr[j] = *(const bf16x8*)&Bs[(wn + j * 16 + l16) * 64 + gcol];
#pragma unroll
      for (int i = 0; i < 4; ++i)
#pragma unroll
        for (int j = 0; j < 4; ++j)
          acc[i][j] = __builtin_amdgcn_mfma_f32_16x16x32_bf16(af[i], bfr[j], acc[i][j], 0, 0, 0);
    }
    __syncthreads();  // all reads done before next iter's DMA overwrite
  }
}

// ======================= 256^2 core (scores/pv) ============================
// Round-4 race-fixed rotated pipeline. 512 threads = 8 waves (2M x 4N);
// per-wave 128x64 out = acc[8][4]. LDS 128 KiB: buf b at b*32768; A k-half s
// at +s*8192; B at +16384+s*8192. Half = 256x32; 16B group g of row r stored
// at g ^ ((r>>1)&3) via pre-swizzled source. See round-4 ledger comments.
DEVI void gemmS(const u16* __restrict__ A, const u16* __restrict__ Bt,
                int lda, int ldb, int m0, int n0, int kEnd, u16* lds,
                floatx4 acc[8][4]) {
  const int tid = threadIdx.x;
  const int wave = tid >> 6, lane = tid & 63;
  const int wm = (wave >> 2) * 128, wn = (wave & 3) * 64;
  const int quad = lane >> 4, l16 = lane & 15;
  const int swe = (quad ^ ((l16 >> 1) & 3)) * 8;  // swizzled group, u16 elems
  const int nkt = kEnd >> 6;

  int dstc[2];
  const u16 *Asp[2], *Bsp[2];
#pragma unroll
  for (int q = 0; q < 2; ++q) {
    int c0 = (q * 8 + wave) * 64;  // wave-uniform chunk base
    int c = c0 + lane;
    int sr = c >> 2;
    int sg = ((c & 3) ^ ((sr >> 1) & 3)) * 8;
    dstc[q] = c0 * 8;
    Asp[q] = A + (size_t)(m0 + sr) * lda + sg;
    Bsp[q] = Bt + (size_t)(n0 + sr) * ldb + sg;
  }
  const int rbA = (wm + l16) * 32 + swe;
  const int rbB = 16384 + (wn + l16) * 32 + swe;

#define STAGE(ktu, isB, sh)                                                  \
  {                                                                          \
    int kc = (ktu) < nkt ? (ktu) : (nkt - 1); /* clamp src; dst keeps slot */ \
    int ks = (kc << 6) + (sh) * 32;                                          \
    int db = (((ktu) & 1) << 15) + (isB) * 16384 + (sh) * 8192;              \
    cp16(((isB) ? Bsp[0] : Asp[0]) + ks, &lds[db + dstc[0]]);                \
    cp16(((isB) ? Bsp[1] : Asp[1]) + ks, &lds[db + dstc[1]]);                \
  }

  bf16x8 a0[8], b0[4];
  STAGE(0, 0, 0); STAGE(0, 1, 0); STAGE(0, 0, 1); STAGE(0, 1, 1);
  STAGE(1, 0, 0); STAGE(1, 1, 0);
  asm volatile("s_waitcnt vmcnt(4)" ::: "memory");  // kt0 landed; (1,h0) in flight
  __builtin_amdgcn_s_barrier();
  __builtin_amdgcn_sched_barrier(0);
#pragma unroll
  for (int i = 0; i < 8; ++i) a0[i] = *(const bf16x8*)&lds[rbA + i * 512];
#pragma unroll
  for (int j = 0; j < 4; ++j) b0[j] = *(const bf16x8*)&lds[rbB + j * 512];

  for (int m = 0; m < nkt; ++m) {
    const int bofs = (m & 1) << 15;
    const int nofs = bofs ^ 32768;
    bf16x8 a1[8], b1[4];
    // step 1: other-buf h1 stage; drain own s0 reads; B1 (h0 WAR gate)
    STAGE(m + 1, 0, 1); STAGE(m + 1, 1, 1);
    asm volatile("s_waitcnt lgkmcnt(0)" ::: "memory");
    __builtin_amdgcn_s_barrier();
    __builtin_amdgcn_sched_barrier(0);
    // step 2: overwrite cur h0; issue s1 fragment reads
    STAGE(m + 2, 0, 0); STAGE(m + 2, 1, 0);
    {
      const int ab = bofs + 8192 + rbA, bb = bofs + 8192 + rbB;
#pragma unroll
      for (int i = 0; i < 8; ++i) a1[i] = *(const bf16x8*)&lds[ab + i * 512];
#pragma unroll
      for (int j = 0; j < 4; ++j) b1[j] = *(const bf16x8*)&lds[bb + j * 512];
    }
    __builtin_amdgcn_sched_barrier(0);
    __builtin_amdgcn_s_setprio(1);
    // step 3: 32 MFMA s0 (covers a1/b1 drain)
#pragma unroll
    for (int i = 0; i < 8; ++i)
#pragma unroll
      for (int j = 0; j < 4; ++j)
        acc[i][j] = __builtin_amdgcn_mfma_f32_16x16x32_bf16(a0[i], b0[j],
                                                            acc[i][j], 0, 0, 0);
    __builtin_amdgcn_sched_barrier(0);
    // step 4: 16 MFMA s1 first half
#pragma unroll
    for (int i = 0; i < 4; ++i)
#pragma unroll
      for (int j = 0; j < 4; ++j)
        acc[i][j] = __builtin_amdgcn_mfma_f32_16x16x32_bf16(a1[i], b1[j],
                                                            acc[i][j], 0, 0, 0);
    __builtin_amdgcn_sched_barrier(0);
    // step 5: B2 — all-waves DMA-visibility gate for kt m+1
    asm volatile("s_waitcnt vmcnt(4)" ::: "memory");
    __builtin_amdgcn_s_barrier();
    __builtin_amdgcn_sched_barrier(0);
    // step 6: next K-tile s0 fragments (safe post-B2)
    {
      const int ab = nofs + rbA, bb = nofs + rbB;
#pragma unroll
      for (int i = 0; i < 8; ++i) a0[i] = *(const bf16x8*)&lds[ab + i * 512];
#pragma unroll
      for (int j = 0; j < 4; ++j) b0[j] = *(const bf16x8*)&lds[bb + j * 512];
    }
    __builtin_amdgcn_sched_barrier(0);
    // step 7: 16 MFMA s1 second half (covers next-s0 drain)
#pragma unroll
    for (int i = 4; i < 8; ++i)
#pragma unroll
      for (int j = 0; j < 4; ++j)
        acc[i][j] = __builtin_amdgcn_mfma_f32_16x16x32_bf16(a1[i], b1[j],
                                                            acc[i][j], 0, 0, 0);
    __builtin_amdgcn_s_setprio(0);
  }
#undef STAGE
}

// ---- QKV projection (128^2 core): y = x @ W^T over all tokens passed.
// z=0->Q, z=1->K (both [t][d]), z=2->V transposed per batch (b = t>>11).
__global__ __launch_bounds__(256, 2)
void proj_kernel(const u16* __restrict__ x, const u16* __restrict__ Wq,
                 const u16* __restrict__ Wk, const u16* __restrict__ Wv,
                 u16* __restrict__ Q, u16* __restrict__ K, u16* __restrict__ Vt) {
  __shared__ __align__(16) u16 As[128 * 64], Bs[128 * 64];
  const int z = blockIdx.z;
  const u16* W = (z == 0) ? Wq : (z == 1) ? Wk : Wv;
  const int m0 = blockIdx.y * 128, n0 = blockIdx.x * 128;
  floatx4 acc[4][4] = {};
  gemm_core(x, W, En, En, m0, n0, En, As, Bs, acc);

  const int lane = threadIdx.x & 63, wave = threadIdx.x >> 6;
  const int wm = (wave >> 1) * 64, wn = (wave & 1) * 64;
  const int quad = lane >> 4, l16 = lane & 15;

  if (z < 2) {
    u16* dst = (z == 0) ? Q : K;
#pragma unroll
    for (int i = 0; i < 4; ++i) {
      int t0 = m0 + wm + i * 16 + quad * 4;       // token index
#pragma unroll
      for (int j = 0; j < 4; ++j) {
        int gn = n0 + wn + j * 16 + l16;
#pragma unroll
        for (int r = 0; r < 4; ++r)
          dst[(size_t)(t0 + r) * Dn + gn] = f2b(acc[i][j][r]);
      }
    }
  } else {
#pragma unroll
    for (int i = 0; i < 4; ++i) {
      int t0 = m0 + wm + i * 16 + quad * 4;       // token index
      int b = t0 >> 11, s0 = t0 & (Sn - 1);
#pragma unroll
      for (int j = 0; j < 4; ++j) {
        int gn = n0 + wn + j * 16 + l16;          // d index
        *(ushort4*)&Vt[((size_t)b * Dn + gn) * Sn + s0] =
            make_ushort4(f2b(acc[i][j][0]), f2b(acc[i][j][1]),
                         f2b(acc[i][j][2]), f2b(acc[i][j][3]));
      }
    }
  }
}

// ---- scores = Q_b @ K_b^T / sqrt(D), causal (256^2 core); z = batch.
__global__ __launch_bounds__(512, 2)
void scores_kernel(const u16* __restrict__ Q, const u16* __restrict__ K,
                   float* __restrict__ Sc) {
  const int b = blockIdx.z;
  const int m0 = blockIdx.y * 256, n0 = blockIdx.x * 256;
  float* C = Sc + (size_t)b * Sn * Sn;
  if (n0 > m0 + 255) {
    const float4 f = make_float4(-1e30f, -1e30f, -1e30f, -1e30f);
    for (int idx = threadIdx.x; idx < 256 * 64; idx += 512) {
      int r = idx >> 6, c4 = (idx & 63) << 2;
      *(float4*)&C[(size_t)(m0 + r) * Sn + n0 + c4] = f;
    }
    return;
  }
  __shared__ __align__(16) u16 lds[65536];
  floatx4 acc[8][4] = {};
  gemmS(Q + (size_t)b * Sn * Dn, K + (size_t)b * Sn * Dn, Dn, Dn, m0, n0, Dn,
        lds, acc);

  const float inv_scale = 0.022097086912079608f;  // 1/sqrt(2048)
  const int lane = threadIdx.x & 63, wave = threadIdx.x >> 6;
  const int wm = (wave >> 2) * 128, wn = (wave & 3) * 64;
  const int quad = lane >> 4, l16 = lane & 15;
#pragma unroll
  for (int mi = 0; mi < 8; ++mi) {
    int gm0 = m0 + wm + mi * 16 + quad * 4;
#pragma unroll
    for (int j = 0; j < 4; ++j) {
      int gn = n0 + wn + j * 16 + l16;
#pragma unroll
      for (int r = 0; r < 4; ++r) {
        float v = acc[mi][j][r] * inv_scale;
        if (gn > gm0 + r) v = -1e30f;
        C[(size_t)(gm0 + r) * Sn + gn] = v;
      }
    }
  }
}

// ---- row softmax over 2048 fp32; write attn bf16 in-place (u16 pitch 2*Sn).
__global__ __launch_bounds__(256)
void softmax_kernel(float* __restrict__ Sc) {
  float* sr = Sc + (size_t)blockIdx.x * Sn;
  const int t = threadIdx.x;
  float4 v0 = ((const float4*)sr)[t];
  float4 v1 = ((const float4*)sr)[t + 256];
  float m = fmaxf(fmaxf(fmaxf(v0.x, v0.y), fmaxf(v0.z, v0.w)),
                  fmaxf(fmaxf(v1.x, v1.y), fmaxf(v1.z, v1.w)));
#pragma unroll
  for (int off = 32; off; off >>= 1) m = fmaxf(m, __shfl_xor(m, off));
  __shared__ float redm[4], reds[4];
  if ((t & 63) == 0) redm[t >> 6] = m;
  __syncthreads();
  m = fmaxf(fmaxf(redm[0], redm[1]), fmaxf(redm[2], redm[3]));

  float e[8];
  e[0] = __expf(v0.x - m); e[1] = __expf(v0.y - m);
  e[2] = __expf(v0.z - m); e[3] = __expf(v0.w - m);
  e[4] = __expf(v1.x - m); e[5] = __expf(v1.y - m);
  e[6] = __expf(v1.z - m); e[7] = __expf(v1.w - m);
  float s = ((e[0] + e[1]) + (e[2] + e[3])) + ((e[4] + e[5]) + (e[6] + e[7]));
#pragma unroll
  for (int off = 32; off; off >>= 1) s += __shfl_xor(s, off);
  if ((t & 63) == 0) reds[t >> 6] = s;
  __syncthreads();
  s = (reds[0] + reds[1]) + (reds[2] + reds[3]);
  float inv = 1.0f / s;

  u16* ar = (u16*)sr;  // all global reads above; in-place bf16 write is safe
  *(ushort4*)&ar[t * 4] =
      make_ushort4(f2b(e[0] * inv), f2b(e[1] * inv), f2b(e[2] * inv), f2b(e[3] * inv));
  *(ushort4*)&ar[(t + 256) * 4] =
      make_ushort4(f2b(e[4] * inv), f2b(e[5] * inv), f2b(e[6] * inv), f2b(e[7] * inv));
}

// ---- out_b = attn @ V via Vt (256^2 core); z = batch; K truncated at diag.
__global__ __launch_bounds__(512, 2)
void pv_kernel(const float* __restrict__ Sc, const u16* __restrict__ Vt,
               float* __restrict__ out) {
  const int b = blockIdx.z;
  const int m0 = blockIdx.y * 256, n0 = blockIdx.x * 256;
  __shared__ __align__(16) u16 lds[65536];
  floatx4 acc[8][4] = {};
  const u16* P = (const u16*)(Sc + (size_t)b * Sn * Sn);  // bf16 attn, pitch 2*Sn
  gemmS(P, Vt + (size_t)b * Dn * Sn, 2 * Sn, Sn, m0, n0, m0 + 256, lds, acc);

  const int lane = threadIdx.x & 63, wave = threadIdx.x >> 6;
  const int wm = (wave >> 2) * 128, wn = (wave & 3) * 64;
  const int quad = lane >> 4, l16 = lane & 15;
  float* ob = out + (size_t)b * Sn * Dn;
#pragma unroll
  for (int mi = 0; mi < 8; ++mi) {
    int gm0 = m0 + wm + mi * 16 + quad * 4;
#pragma unroll
    for (int j = 0; j < 4; ++j) {
      int gn = n0 + wn + j * 16 + l16;
#pragma unroll
      for (int r = 0; r < 4; ++r)
        ob[(size_t)(gm0 + r) * Dn + gn] = acc[mi][j][r];
    }
  }
}

extern "C" void kernel_launch(void* const* d_in, const int* in_sizes, int n_in,
                              void* d_out, int out_size, void* d_ws, size_t ws_size,
                              hipStream_t stream) {
  const float* x  = (const float*)d_in[0];   // setup_inputs order: x, Wk, Wq, Wv (fp32)
  const float* Wk = (const float*)d_in[1];
  const float* Wq = (const float*)d_in[2];
  const float* Wv = (const float*)d_in[3];
  float* out = (float*)d_out;

  dim3 blk(256), blk5(512);
  const int nW = Dn * En;                    // 4M elems per weight
  const size_t MiB = 1ull << 20;

  if (ws_size >= 184 * MiB) {
    // ---- fused path: Wqb|Wkb|Wvb | xb(all) | K(all) | Vt(all) | Sc(all fp32)
    u16* Wqb = (u16*)d_ws;
    u16* Wkb = Wqb + (size_t)nW;
    u16* Wvb = Wkb + (size_t)nW;
    u16* xb  = Wvb + (size_t)nW;             // [8192][2048]
    u16* Kall = xb + (size_t)Bn * Sn * En;   // [8192][2048]
    u16* Vtall = Kall + (size_t)Bn * Sn * Dn;  // [b][d][s]
    float* Sc = (float*)(Vtall + (size_t)Bn * Dn * Sn);  // [b][s][s]
    u16* Qall = (u16*)out;                   // 32 MiB of the 64 MiB out; pv overwrites

    cvt_kernel<<<nW / 2048, blk, 0, stream>>>(Wq, Wqb, nW);
    cvt_kernel<<<nW / 2048, blk, 0, stream>>>(Wk, Wkb, nW);
    cvt_kernel<<<nW / 2048, blk, 0, stream>>>(Wv, Wvb, nW);
    cvt_kernel<<<(Bn * Sn * En) / 2048, blk, 0, stream>>>(x, xb, Bn * Sn * En);
    proj_kernel<<<dim3(Dn / 128, (Bn * Sn) / 128, 3), blk, 0, stream>>>(
        xb, Wqb, Wkb, Wvb, Qall, Kall, Vtall);
    scores_kernel<<<dim3(Sn / 256, Sn / 256, Bn), blk5, 0, stream>>>(Qall, Kall, Sc);
    softmax_kernel<<<dim3(Bn * Sn), blk, 0, stream>>>(Sc);
    pv_kernel<<<dim3(Dn / 256, Sn / 256, Bn), blk5, 0, stream>>>(Sc, Vtall, out);
  } else {
    // ---- sequential fallback (56 MiB): Wqb|Wkb|Wvb | Sc (xb aliased) | Kb | Vtb
    u16* Wqb = (u16*)d_ws;
    u16* Wkb = Wqb + (size_t)nW;
    u16* Wvb = Wkb + (size_t)nW;
    float* Sc = (float*)(Wvb + (size_t)nW);
    u16* xb  = (u16*)Sc;                     // dead once scores_kernel runs
    u16* Kb  = (u16*)(Sc + (size_t)Sn * Sn);
    u16* Vtb = Kb + (size_t)Sn * Dn;

    cvt_kernel<<<nW / 2048, blk, 0, stream>>>(Wq, Wqb, nW);
    cvt_kernel<<<nW / 2048, blk, 0, stream>>>(Wk, Wkb, nW);
    cvt_kernel<<<nW / 2048, blk, 0, stream>>>(Wv, Wvb, nW);
    for (int b = 0; b < Bn; ++b) {
      const float* xf = x + (size_t)b * Sn * En;
      float* outb = out + (size_t)b * Sn * Dn;
      u16* Qb = (u16*)outb;                  // bf16 Q in out_b's region; pv overwrites
      cvt_kernel<<<(Sn * En) / 2048, blk, 0, stream>>>(xf, xb, Sn * En);
      proj_kernel<<<dim3(Dn / 128, Sn / 128, 3), blk, 0, stream>>>(xb, Wqb, Wkb, Wvb,
                                                                   Qb, Kb, Vtb);
      scores_kernel<<<dim3(Sn / 256, Sn / 256, 1), blk5, 0, stream>>>(Qb, Kb, Sc);
      softmax_kernel<<<dim3(Sn), blk, 0, stream>>>(Sc);
      pv_kernel<<<dim3(Dn / 256, Sn / 256, 1), blk5, 0, stream>>>(Sc, Vtb, outb);
    }
  }
}

// Round 7
// 477.919 us; speedup vs baseline: 1.0380x; 1.0248x over previous
//
#include <hip/hip_runtime.h>
#include <hip/hip_bf16.h>
#include <stdint.h>

// GPT self-attention, B=4 S=2048 E=2048 D=2048. FP32 in/out, bf16 MFMA internally.
// Round-11: round-0 kernel (best measured: 471-482us) + middle-section fixes:
//  (1) scores: upper-triangle tiles return WITHOUT the -1e30 fill (30 MB saved);
//      softmax now masks cols>row internally so fills are never read.
//  (2) softmax: causal-prefix — loads only chunks with c<=row (saves ~33 MB
//      read), writes bf16 only cols [0, wlim=(row&~127)+128) (saves ~17 MB
//      write); wlim exactly covers pv's K-range (kEnd=m0+128), beyond-wlim
//      cols are never read. Loads still all precede the first __syncthreads,
//      writes follow the last -> in-place bf16 overwrite stays race-free.
//  (3) pv: y-reversed tile map so 32-kt blocks dispatch first (kills ~16us
//      ragged tail from shortest-first order).
//  (4) single cvt4 kernel replaces 4 serialized cvt launches (fused path).
// GEMM cores are round-0 verbatim (proj 190us @ 52% MfmaUtil, 3 blocks/CU).

typedef unsigned short u16;
typedef unsigned int u32;
typedef __bf16 bf16x8 __attribute__((ext_vector_type(8)));
typedef float floatx4 __attribute__((ext_vector_type(4)));

#define DEVI __device__ __forceinline__

constexpr int Bn = 4, Sn = 2048, En = 2048, Dn = 2048;
constexpr int BM = 128, BN = 128, BK = 64;

DEVI u16 f2b(float f) {  // round-to-nearest-even f32 -> bf16
  union { float f; u32 u; } v; v.f = f;
  u32 r = v.u + 0x7FFFu + ((v.u >> 16) & 1u);
  return (u16)(r >> 16);
}

DEVI void cp16(const u16* g, u16* l) {  // async global->LDS, 16 B per lane
  __builtin_amdgcn_global_load_lds(
      (const __attribute__((address_space(1))) void*)g,
      (__attribute__((address_space(3))) void*)l, 16, 0, 0);
}

// ---- fp32 -> bf16 elementwise, n multiple of 2048; 8 elems/thread.
__global__ __launch_bounds__(256)
void cvt_kernel(const float* __restrict__ src, u16* __restrict__ dst, int n) {
  int i = (blockIdx.x * 256 + threadIdx.x) * 8;
  if (i >= n) return;
  float4 a = *(const float4*)&src[i];
  float4 b = *(const float4*)&src[i + 4];
  *(ushort4*)&dst[i]     = make_ushort4(f2b(a.x), f2b(a.y), f2b(a.z), f2b(a.w));
  *(ushort4*)&dst[i + 4] = make_ushort4(f2b(b.x), f2b(b.y), f2b(b.z), f2b(b.w));
}

// ---- fused 4-tensor cvt: blocks [0,2048)Wq [2048,4096)Wk [4096,6144)Wv rest x.
__global__ __launch_bounds__(256)
void cvt4_kernel(const float* __restrict__ x, const float* __restrict__ Wq,
                 const float* __restrict__ Wk, const float* __restrict__ Wv,
                 u16* __restrict__ xb, u16* __restrict__ Wqb,
                 u16* __restrict__ Wkb, u16* __restrict__ Wvb) {
  int bi = blockIdx.x;
  const float* src; u16* dst; int base;
  if (bi < 2048)      { src = Wq; dst = Wqb; base = bi; }
  else if (bi < 4096) { src = Wk; dst = Wkb; base = bi - 2048; }
  else if (bi < 6144) { src = Wv; dst = Wvb; base = bi - 4096; }
  else                { src = x;  dst = xb;  base = bi - 6144; }
  int i = (base * 256 + threadIdx.x) * 8;
  float4 a = *(const float4*)&src[i];
  float4 b = *(const float4*)&src[i + 4];
  *(ushort4*)&dst[i]     = make_ushort4(f2b(a.x), f2b(a.y), f2b(a.z), f2b(a.w));
  *(ushort4*)&dst[i + 4] = make_ushort4(f2b(b.x), f2b(b.y), f2b(b.z), f2b(b.w));
}

// C[m0..+128, n0..+128] += A[*,K] * Bt[*,K]^T (row-major, K contiguous), bf16, fp32 acc.
// LDS tiles 128x64 unpadded (LP=64), 8-elem group g of row r stored at g^(r&7).
// Fragment maps (m89/m91/m92): A[m=lane&15][k=quad*8+j], Bt[n=lane&15][k=quad*8+j],
// C/D col=lane&15, row=quad*4+reg.
DEVI void gemm_core(const u16* __restrict__ A, const u16* __restrict__ Bt,
                    int lda, int ldb, int m0, int n0, int kEnd,
                    u16* As, u16* Bs, floatx4 acc[4][4]) {
  const int tid = threadIdx.x;
  const int lane = tid & 63;
  const int wave = tid >> 6;
  const int wm = (wave >> 1) * 64;
  const int wn = (wave & 1) * 64;
  const int quad = lane >> 4;
  const int l16 = lane & 15;
  const int sw = l16 & 7;  // r&7 for fragment rows (wm,wn,i*16 are multiples of 8)

  // per-lane staging coords, constant across k-iters
  int srow[4], sgl[4], sdst[4];
#pragma unroll
  for (int u = 0; u < 4; ++u) {
    int c0 = wave * 256 + u * 64;       // wave-uniform chunk base
    int c = c0 + lane;                  // this lane's 16B chunk
    srow[u] = c >> 3;
    sgl[u] = (c & 7) ^ (srow[u] & 7);   // logical column-group under swizzle
    sdst[u] = c0 * 8;                   // LDS elem offset (wave-uniform)
  }

  for (int k0 = 0; k0 < kEnd; k0 += BK) {
#pragma unroll
    for (int u = 0; u < 4; ++u) {
      cp16(&A[(size_t)(m0 + srow[u]) * lda + k0 + sgl[u] * 8], &As[sdst[u]]);
      cp16(&Bt[(size_t)(n0 + srow[u]) * ldb + k0 + sgl[u] * 8], &Bs[sdst[u]]);
    }
    __syncthreads();  // drains vmcnt -> DMA complete
#pragma unroll
    for (int s = 0; s < 2; ++s) {
      const int gcol = ((s * 4 + quad) ^ sw) * 8;  // swizzled group offset (elems)
      bf16x8 af[4], bfr[4];
#pragma unroll
      for (int i = 0; i < 4; ++i)
        af[i] = *(const bf16x8*)&As[(wm + i * 16 + l16) * 64 + gcol];
#pragma unroll
      for (int j = 0; j < 4; ++j)
        bfr[j] = *(const bf16x8*)&Bs[(wn + j * 16 + l16) * 64 + gcol];
#pragma unroll
      for (int i = 0; i < 4; ++i)
#pragma unroll
        for (int j = 0; j < 4; ++j)
          acc[i][j] = __builtin_amdgcn_mfma_f32_16x16x32_bf16(af[i], bfr[j], acc[i][j], 0, 0, 0);
    }
    __syncthreads();  // all reads done before next iter's DMA overwrite
  }
}

// ---- QKV projection: y = x @ W^T over all tokens passed (grid.y*128 of them).
// z=0->Q, z=1->K (both [t][d]), z=2->V transposed per batch (b = t>>11).
__global__ __launch_bounds__(256, 2)
void proj_kernel(const u16* __restrict__ x, const u16* __restrict__ Wq,
                 const u16* __restrict__ Wk, const u16* __restrict__ Wv,
                 u16* __restrict__ Q, u16* __restrict__ K, u16* __restrict__ Vt) {
  __shared__ __align__(16) u16 As[BM * 64], Bs[BN * 64];
  const int z = blockIdx.z;
  const u16* W = (z == 0) ? Wq : (z == 1) ? Wk : Wv;
  const int m0 = blockIdx.y * BM, n0 = blockIdx.x * BN;
  floatx4 acc[4][4] = {};
  gemm_core(x, W, En, En, m0, n0, En, As, Bs, acc);

  const int lane = threadIdx.x & 63, wave = threadIdx.x >> 6;
  const int wm = (wave >> 1) * 64, wn = (wave & 1) * 64;
  const int quad = lane >> 4, l16 = lane & 15;

  if (z < 2) {
    u16* dst = (z == 0) ? Q : K;
#pragma unroll
    for (int i = 0; i < 4; ++i) {
      int t0 = m0 + wm + i * 16 + quad * 4;       // token index
#pragma unroll
      for (int j = 0; j < 4; ++j) {
        int gn = n0 + wn + j * 16 + l16;
#pragma unroll
        for (int r = 0; r < 4; ++r)
          dst[(size_t)(t0 + r) * Dn + gn] = f2b(acc[i][j][r]);
      }
    }
  } else {
#pragma unroll
    for (int i = 0; i < 4; ++i) {
      int t0 = m0 + wm + i * 16 + quad * 4;       // token index
      int b = t0 >> 11, s0 = t0 & (Sn - 1);
#pragma unroll
      for (int j = 0; j < 4; ++j) {
        int gn = n0 + wn + j * 16 + l16;          // d index
        *(ushort4*)&Vt[((size_t)b * Dn + gn) * Sn + s0] =
            make_ushort4(f2b(acc[i][j][0]), f2b(acc[i][j][1]),
                         f2b(acc[i][j][2]), f2b(acc[i][j][3]));
      }
    }
  }
}

// ---- scores = Q_b @ K_b^T / sqrt(D), causal; z = batch.
// Upper-triangle tiles: plain return (softmax masks cols>row internally).
__global__ __launch_bounds__(256, 2)
void scores_kernel(const u16* __restrict__ Q, const u16* __restrict__ K,
                   float* __restrict__ Sc) {
  const int b = blockIdx.z;
  const int m0 = blockIdx.y * BM, n0 = blockIdx.x * BN;
  if (n0 > m0 + (BM - 1)) return;  // never read: softmax is causal-aware
  float* C = Sc + (size_t)b * Sn * Sn;
  __shared__ __align__(16) u16 As[BM * 64], Bs[BN * 64];
  floatx4 acc[4][4] = {};
  gemm_core(Q + (size_t)b * Sn * Dn, K + (size_t)b * Sn * Dn, Dn, Dn, m0, n0, Dn,
            As, Bs, acc);

  const float inv_scale = 0.022097086912079608f;  // 1/sqrt(2048)
  const int lane = threadIdx.x & 63, wave = threadIdx.x >> 6;
  const int wm = (wave >> 1) * 64, wn = (wave & 1) * 64;
  const int quad = lane >> 4, l16 = lane & 15;
#pragma unroll
  for (int i = 0; i < 4; ++i) {
    int gm0 = m0 + wm + i * 16 + quad * 4;
#pragma unroll
    for (int j = 0; j < 4; ++j) {
      int gn = n0 + wn + j * 16 + l16;
#pragma unroll
      for (int r = 0; r < 4; ++r) {
        float v = acc[i][j][r] * inv_scale;
        if (gn > gm0 + r) v = -1e30f;   // in-tile diagonal mask
        C[(size_t)(gm0 + r) * Sn + gn] = v;
      }
    }
  }
}

// ---- causal row softmax over cols [0,row]; writes attn bf16 in-place for
// cols [0, wlim=(row&~127)+128) only (exactly pv's K-range). Loads all precede
// the first __syncthreads; writes follow the last -> in-place overwrite safe.
__global__ __launch_bounds__(256)
void softmax_kernel(float* __restrict__ Sc) {
  const int row = blockIdx.x & (Sn - 1);
  float* sr = Sc + (size_t)blockIdx.x * Sn;
  const int t = threadIdx.x;
  const int c0 = t * 4, c1 = 1024 + t * 4;
  float4 v0 = make_float4(-1e30f, -1e30f, -1e30f, -1e30f), v1 = v0;
  if (c0 <= row) v0 = ((const float4*)sr)[t];
  if (c1 <= row) v1 = ((const float4*)sr)[t + 256];
  // mask cols > row (diagonal chunk partially valid)
  if (c0 + 1 > row) v0.y = -1e30f;
  if (c0 + 2 > row) v0.z = -1e30f;
  if (c0 + 3 > row) v0.w = -1e30f;
  if (c1 + 1 > row) v1.y = -1e30f;
  if (c1 + 2 > row) v1.z = -1e30f;
  if (c1 + 3 > row) v1.w = -1e30f;
  float m = fmaxf(fmaxf(fmaxf(v0.x, v0.y), fmaxf(v0.z, v0.w)),
                  fmaxf(fmaxf(v1.x, v1.y), fmaxf(v1.z, v1.w)));
#pragma unroll
  for (int off = 32; off; off >>= 1) m = fmaxf(m, __shfl_xor(m, off));
  __shared__ float redm[4], reds[4];
  if ((t & 63) == 0) redm[t >> 6] = m;
  __syncthreads();
  m = fmaxf(fmaxf(redm[0], redm[1]), fmaxf(redm[2], redm[3]));  // finite: >= diag

  float e[8];
  e[0] = __expf(v0.x - m); e[1] = __expf(v0.y - m);  // -1e30 lanes underflow to 0
  e[2] = __expf(v0.z - m); e[3] = __expf(v0.w - m);
  e[4] = __expf(v1.x - m); e[5] = __expf(v1.y - m);
  e[6] = __expf(v1.z - m); e[7] = __expf(v1.w - m);
  float s = ((e[0] + e[1]) + (e[2] + e[3])) + ((e[4] + e[5]) + (e[6] + e[7]));
#pragma unroll
  for (int off = 32; off; off >>= 1) s += __shfl_xor(s, off);
  if ((t & 63) == 0) reds[t >> 6] = s;
  __syncthreads();
  s = (reds[0] + reds[1]) + (reds[2] + reds[3]);
  float inv = 1.0f / s;

  const int wlim = (row & ~(BM - 1)) + BM;  // pv reads exactly cols [0, wlim)
  u16* ar = (u16*)sr;
  if (c0 < wlim)
    *(ushort4*)&ar[t * 4] =
        make_ushort4(f2b(e[0] * inv), f2b(e[1] * inv), f2b(e[2] * inv), f2b(e[3] * inv));
  if (c1 < wlim)
    *(ushort4*)&ar[(t + 256) * 4] =
        make_ushort4(f2b(e[4] * inv), f2b(e[5] * inv), f2b(e[6] * inv), f2b(e[7] * inv));
}

// ---- out_b = attn @ V via Vt; z = batch; K-loop truncated at diagonal.
// y-REVERSED tile map: longest K-loops (m0 large) dispatch first -> no tail.
__global__ __launch_bounds__(256, 2)
void pv_kernel(const float* __restrict__ Sc, const u16* __restrict__ Vt,
               float* __restrict__ out) {
  const int b = blockIdx.z;
  const int m0 = ((int)gridDim.y - 1 - (int)blockIdx.y) * BM;
  const int n0 = blockIdx.x * BN;
  __shared__ __align__(16) u16 As[BM * 64], Bs[BN * 64];
  floatx4 acc[4][4] = {};
  const u16* P = (const u16*)(Sc + (size_t)b * Sn * Sn);  // bf16 attn, pitch 2*Sn
  gemm_core(P, Vt + (size_t)b * Dn * Sn, 2 * Sn, Sn, m0, n0, m0 + BM, As, Bs, acc);

  const int lane = threadIdx.x & 63, wave = threadIdx.x >> 6;
  const int wm = (wave >> 1) * 64, wn = (wave & 1) * 64;
  const int quad = lane >> 4, l16 = lane & 15;
  float* ob = out + (size_t)b * Sn * Dn;
#pragma unroll
  for (int i = 0; i < 4; ++i) {
    int gm0 = m0 + wm + i * 16 + quad * 4;
#pragma unroll
    for (int j = 0; j < 4; ++j) {
      int gn = n0 + wn + j * 16 + l16;
#pragma unroll
      for (int r = 0; r < 4; ++r)
        ob[(size_t)(gm0 + r) * Dn + gn] = acc[i][j][r];
    }
  }
}

extern "C" void kernel_launch(void* const* d_in, const int* in_sizes, int n_in,
                              void* d_out, int out_size, void* d_ws, size_t ws_size,
                              hipStream_t stream) {
  const float* x  = (const float*)d_in[0];   // setup_inputs order: x, Wk, Wq, Wv (fp32)
  const float* Wk = (const float*)d_in[1];
  const float* Wq = (const float*)d_in[2];
  const float* Wv = (const float*)d_in[3];
  float* out = (float*)d_out;

  dim3 blk(256);
  const int nW = Dn * En;                    // 4M elems per weight
  const size_t MiB = 1ull << 20;

  if (ws_size >= 184 * MiB) {
    // ---- fused path: Wqb|Wkb|Wvb | xb(all) | K(all) | Vt(all) | Sc(all fp32)
    u16* Wqb = (u16*)d_ws;
    u16* Wkb = Wqb + (size_t)nW;
    u16* Wvb = Wkb + (size_t)nW;
    u16* xb  = Wvb + (size_t)nW;             // [8192][2048]
    u16* Kall = xb + (size_t)Bn * Sn * En;   // [8192][2048]
    u16* Vtall = Kall + (size_t)Bn * Sn * Dn;  // [b][d][s]
    float* Sc = (float*)(Vtall + (size_t)Bn * Dn * Sn);  // [b][s][s]
    u16* Qall = (u16*)out;                   // 32 MiB of the 64 MiB out; pv overwrites

    cvt4_kernel<<<3 * (nW / 2048) + (Bn * Sn * En) / 2048, blk, 0, stream>>>(
        x, Wq, Wk, Wv, xb, Wqb, Wkb, Wvb);
    proj_kernel<<<dim3(Dn / BN, (Bn * Sn) / BM, 3), blk, 0, stream>>>(
        xb, Wqb, Wkb, Wvb, Qall, Kall, Vtall);
    scores_kernel<<<dim3(Sn / BN, Sn / BM, Bn), blk, 0, stream>>>(Qall, Kall, Sc);
    softmax_kernel<<<dim3(Bn * Sn), blk, 0, stream>>>(Sc);
    pv_kernel<<<dim3(Dn / BN, Sn / BM, Bn), blk, 0, stream>>>(Sc, Vtall, out);
  } else {
    // ---- sequential fallback (proven, 56 MiB): Wqb|Wkb|Wvb | Sc (xb aliased) | Kb | Vtb
    u16* Wqb = (u16*)d_ws;
    u16* Wkb = Wqb + (size_t)nW;
    u16* Wvb = Wkb + (size_t)nW;
    float* Sc = (float*)(Wvb + (size_t)nW);
    u16* xb  = (u16*)Sc;                     // dead once scores_kernel runs
    u16* Kb  = (u16*)(Sc + (size_t)Sn * Sn);
    u16* Vtb = Kb + (size_t)Sn * Dn;

    cvt_kernel<<<nW / 2048, blk, 0, stream>>>(Wq, Wqb, nW);
    cvt_kernel<<<nW / 2048, blk, 0, stream>>>(Wk, Wkb, nW);
    cvt_kernel<<<nW / 2048, blk, 0, stream>>>(Wv, Wvb, nW);
    for (int b = 0; b < Bn; ++b) {
      const float* xf = x + (size_t)b * Sn * En;
      float* outb = out + (size_t)b * Sn * Dn;
      u16* Qb = (u16*)outb;                  // bf16 Q in out_b's region; pv overwrites
      cvt_kernel<<<(Sn * En) / 2048, blk, 0, stream>>>(xf, xb, Sn * En);
      proj_kernel<<<dim3(Dn / BN, Sn / BM, 3), blk, 0, stream>>>(xb, Wqb, Wkb, Wvb,
                                                                 Qb, Kb, Vtb);
      scores_kernel<<<dim3(Sn / BN, Sn / BM, 1), blk, 0, stream>>>(Qb, Kb, Sc);
      softmax_kernel<<<dim3(Sn), blk, 0, stream>>>(Sc);
      pv_kernel<<<dim3(Dn / BN, Sn / BM, 1), blk, 0, stream>>>(Sc, Vtb, outb);
    }
  }
}